// Round 11
// baseline (388.386 us; speedup 1.0000x reference)
//
#include <hip/hip_runtime.h>
#include <hip/hip_bf16.h>
#include <math.h>

#define NN 1024
#define BB 4
#define HH 8
#define DD 256
#define LL 4
#define DKK 32
#define MM 4096
#define EPSF 1e-6f
#define LOG2EF 1.4426950408889634f
#define SCLOG2E 0.2550348625f   /* (1/sqrt(32)) * log2(e) */

typedef __attribute__((ext_vector_type(8))) short short8;
typedef __attribute__((ext_vector_type(4))) float f32x4;
typedef unsigned int u32;

__device__ __forceinline__ unsigned short f2bf(float f) {
    __hip_bfloat16 h = __float2bfloat16(f);
    return *(unsigned short*)&h;
}
__device__ __forceinline__ float bf2f(unsigned short u) {
    unsigned v = ((unsigned)u) << 16;
    return __builtin_bit_cast(float, v);
}

// ---------------------------------------------------------------------------
// init: every block does one prologue row; blocks 0..383 also transpose a
// weight tile; blocks 384..1407 swizzle the bias in the SWAPPED-QK layout
// (verified in R4/R8): value jj=f*4+r at lane (qd,cc) = bias[q=cc][k=kt*64+
// f*16+qd*4+r], pre-scaled by log2(e) for exp2 softmax.
// ---------------------------------------------------------------------------
__global__ __launch_bounds__(256) void init_kernel(
    const float* __restrict__ x, const int* __restrict__ deg_in,
    const int* __restrict__ deg_out, const float* __restrict__ svd,
    const float* __restrict__ in_emb, const float* __restrict__ out_emb,
    const float* __restrict__ Wsvd, const float* __restrict__ bsvd,
    const float* __restrict__ Wq, const float* __restrict__ Wk,
    const float* __restrict__ Wv, const float* __restrict__ Wa,
    const float* __restrict__ W1, const float* __restrict__ W2,
    const int* __restrict__ sp, const float* __restrict__ spemb,
    float* __restrict__ h, short* __restrict__ hb,
    short* __restrict__ Wt, short* __restrict__ bsw)
{
    int blk = blockIdx.x;
    int tid = threadIdx.x;
    {
        int n = blk & (NN - 1);
        int di = deg_in[n], dou = deg_out[n];
        float acc = x[(size_t)blk * DD + tid] + in_emb[(size_t)di * DD + tid]
                  + out_emb[(size_t)dou * DD + tid] + bsvd[tid];
        const float* sv = &svd[n * 32];
#pragma unroll
        for (int j = 0; j < 32; ++j) {
            float v = sv[j];
            v = (j < 16) ? v : -v;
            acc += v * Wsvd[j * DD + tid];
        }
        h[(size_t)blk * DD + tid] = acc;
        hb[(size_t)blk * DD + tid] = (short)f2bf(acc);
    }
    if (blk < 384) {
        __shared__ float t[64][65];
        int z = blk >> 4, tile = blk & 15;
        int name = z >> 2;
        const float* srcs[6] = {Wq, Wk, Wv, Wa, W1, W2};
        const float* W = srcs[name] + (size_t)(z & 3) * DD * DD;
        short* dst = Wt + (size_t)z * DD * DD;
        int r0 = (tile >> 2) * 64, c0 = (tile & 3) * 64;
#pragma unroll
        for (int i = 0; i < 16; ++i) {
            int idx = i * 256 + tid;
            int r = idx >> 6, cc = idx & 63;
            t[r][cc] = W[(size_t)(r0 + r) * DD + c0 + cc];
        }
        __syncthreads();
#pragma unroll
        for (int i = 0; i < 16; ++i) {
            int idx = i * 256 + tid;
            int n = idx >> 6, kk = idx & 63;
            dst[(size_t)(c0 + n) * DD + r0 + kk] = (short)f2bf(t[kk][n]);
        }
    } else if (blk < 1408) {
        int bb = blk - 384;
        int part = bb & 3;                      // f == part
        int tt = (bb >> 2) * 256 + tid;         // (q16, kt, lane)
        int ln = tt & 63, kt = (tt >> 6) & 15, q16 = tt >> 10;
        int qd = ln >> 4, cc = ln & 15;
        int row = q16 * 16 + cc;                // q index (swapped layout)
        unsigned buf[8][2];
#pragma unroll
        for (int r = 0; r < 4; ++r) {
            int colj = kt * 64 + part * 16 + qd * 4 + r;   // k index
            int pp = sp[row * NN + colj];
            float4 e0 = *(const float4*)&spemb[pp * 8];
            float4 e1 = *(const float4*)&spemb[pp * 8 + 4];
            float ev[8] = {e0.x, e0.y, e0.z, e0.w, e1.x, e1.y, e1.z, e1.w};
#pragma unroll
            for (int hh = 0; hh < 8; ++hh) {
                unsigned short u = f2bf(ev[hh] * LOG2EF);
                if (r & 1) buf[hh][r >> 1] |= ((unsigned)u) << 16;
                else       buf[hh][r >> 1] = u;
            }
        }
#pragma unroll
        for (int hh = 0; hh < 8; ++hh) {
            uint2* dst = (uint2*)&bsw[(((size_t)hh * 64 + q16) * 16 + kt) * 1024
                                      + (size_t)ln * 16 + part * 4];
            *dst = make_uint2(buf[hh][0], buf[hh][1]);
        }
    }
}

// ---------------------------------------------------------------------------
// QKV bf16 GEMM (layer 0 only), wave = 16x16 tile. Grid (MM/16, 4, 3).
// q pre-scaled by scale*log2e (exp2 softmax).
// ---------------------------------------------------------------------------
__global__ __launch_bounds__(256) void gemm_qkv_kernel(
    const short* __restrict__ A,
    const short* __restrict__ Wtq, const short* __restrict__ Wtk,
    const short* __restrict__ Wtv,
    const float* __restrict__ bq, const float* __restrict__ bk,
    const float* __restrict__ bv,
    short* __restrict__ qo, short* __restrict__ ko, short* __restrict__ vo)
{
    int z = blockIdx.z;
    const short* Wt = (z == 0) ? Wtq : (z == 1) ? Wtk : Wtv;
    const float* bs = (z == 0) ? bq : (z == 1) ? bk : bv;
    int tid = threadIdx.x, wave = tid >> 6, lane = tid & 63;
    int quad = lane >> 4, c = lane & 15;
    int m0 = blockIdx.x * 16;
    int n0 = blockIdx.y * 64 + wave * 16;
    f32x4 acc = {0.f, 0.f, 0.f, 0.f};
    const short* Ap = &A[(size_t)(m0 + c) * DD];
#pragma unroll
    for (int ks = 0; ks < 8; ++ks) {
        short8 af = *(const short8*)&Ap[ks * 32 + quad * 8];
        short8 bf = *(const short8*)&Wt[(size_t)(n0 + c) * DD + ks * 32 + quad * 8];
        acc = __builtin_amdgcn_mfma_f32_16x16x32_bf16(af, bf, acc, 0, 0, 0);
    }
    int b = m0 >> 10;
    int tok0 = (m0 & (NN - 1)) + quad * 4;
    int col = n0 + c;
    int head = col >> 5, dk = col & 31;
    int bh = b * 8 + head;
    float bv2 = bs[col];
    if (z == 2) {
        ushort4 pk;
        pk.x = f2bf(acc[0] + bv2); pk.y = f2bf(acc[1] + bv2);
        pk.z = f2bf(acc[2] + bv2); pk.w = f2bf(acc[3] + bv2);
        *(ushort4*)&vo[((size_t)bh * DKK + dk) * NN + tok0] = pk;
    } else {
        short* out = (z == 0) ? qo : ko;
        float sc = (z == 0) ? SCLOG2E : 1.0f;
#pragma unroll
        for (int r = 0; r < 4; ++r)
            out[((size_t)bh * NN + tok0 + r) * DKK + dk] =
                (short)f2bf((acc[r] + bv2) * sc);
    }
}

// ---------------------------------------------------------------------------
// Attention kernel: 256 thr = 4 waves (wave = q-tile), grid 512 -> TWO
// independent blocks per CU (decoupled barrier domains). Shared K/V LDS
// staging (4-way reuse). Swapped QK^T (mfma(K,Q)); P transpose = 4x
// ds_write_b64; lane-scalar l-sum. blk%8 == head pins each head's K/V +
// 2MB bias slab to one XCD L2. [R8/R10 configuration — unchanged]
// ---------------------------------------------------------------------------
__global__ __launch_bounds__(256) void attn_kernel(
    const short* __restrict__ q, const short* __restrict__ k,
    const short* __restrict__ vt, const short* __restrict__ bsw,
    short* __restrict__ obuf)
{
    int blk = blockIdx.x;
    int head = blk & 7;
    int b = (blk >> 3) & 3;
    int qg = blk >> 5;            // 0..15
    int tid = threadIdx.x, wave = tid >> 6, lane = tid & 63;
    int quad = lane >> 4, c = lane & 15;
    int bh = b * 8 + head;
    int qt = qg * 4 + wave;
    int q0 = qt * 16;
    int m0 = b * NN + q0;

    __shared__ short Ks[2][64][32];   // 8 KB (dbuf K tile, [tok][dk])
    __shared__ short Vs[2][32][64];   // 8 KB (dbuf V tile, [dk][tok])
    __shared__ short P[4][16][72];    // 9.2 KB wave-private P ([q][k], row-major)
    const f32x4 zero = {0.f, 0.f, 0.f, 0.f};

    // stage tile t into buffer buf: each wave stages a K-quarter + V-quarter.
    auto stage = [&](int t, int buf) {
        const short* ksrc = &k[((size_t)bh * NN + t * 64 + wave * 16 + (lane >> 2)) * DKK
                               + (lane & 3) * 8];
        __builtin_amdgcn_global_load_lds(
            (const __attribute__((address_space(1))) u32*)ksrc,
            (__attribute__((address_space(3))) u32*)&Ks[buf][wave * 16][0], 16, 0, 0);
        const short* vsrc = &vt[((size_t)bh * DKK + wave * 8 + (lane >> 3)) * NN
                                + t * 64 + (lane & 7) * 8];
        __builtin_amdgcn_global_load_lds(
            (const __attribute__((address_space(1))) u32*)vsrc,
            (__attribute__((address_space(3))) u32*)&Vs[buf][wave * 8][0], 16, 0, 0);
    };

    stage(0, 0);

    short8 qf = *(const short8*)&q[((size_t)bh * NN + q0 + c) * DKK + quad * 8];
    const short* bbase = &bsw[(((size_t)head * 64 + qt) * 16) * 1024 + (size_t)lane * 16];
    short8 bc0 = *(const short8*)bbase;
    short8 bc1 = *(const short8*)(bbase + 8);

    f32x4 Oa0 = zero, Oa1 = zero;
    float lsum = 0.f;

    __syncthreads();   // tile 0 staged (barrier drains vmcnt)

    for (int kti = 0; kti < 16; ++kti) {
        int cur = kti & 1;
        // issue next tile's staging first (hides under this tile's compute)
        if (kti < 15) stage(kti + 1, cur ^ 1);
        // K fragments (A-operand: K rows) from shared LDS
        short8 kf[4];
#pragma unroll
        for (int f = 0; f < 4; ++f)
            kf[f] = *(const short8*)&Ks[cur][f * 16 + c][quad * 8];
        // V fragments from shared LDS
        short8 vf0[2], vf1[2];
#pragma unroll
        for (int kc = 0; kc < 2; ++kc) {
            vf0[kc] = *(const short8*)&Vs[cur][c][kc * 32 + quad * 8];
            vf1[kc] = *(const short8*)&Vs[cur][16 + c][kc * 32 + quad * 8];
        }
        // S^T = K . Q^T : lane holds S[k=f*16+quad*4+r][q=c]
        f32x4 s[4];
#pragma unroll
        for (int f = 0; f < 4; ++f)
            s[f] = __builtin_amdgcn_mfma_f32_16x16x32_bf16(kf[f], qf, zero, 0, 0, 0);
        // prefetch next bias tile
        short8 bn0 = bc0, bn1 = bc1;
        if (kti < 15) {
            const short* bp = bbase + (size_t)(kti + 1) * 1024;
            bn0 = *(const short8*)bp;
            bn1 = *(const short8*)(bp + 8);
        }
        // exp2(s + bias); pack 4 k-consecutive P values -> one b64 LDS write
#pragma unroll
        for (int f = 0; f < 4; ++f) {
            ushort4 pk;
#pragma unroll
            for (int r = 0; r < 4; ++r) {
                int jj = f * 4 + r;
                unsigned short uu = (unsigned short)((jj < 8) ? bc0[jj] : bc1[jj - 8]);
                float p = __builtin_amdgcn_exp2f(s[f][r] + bf2f(uu));
                lsum += p;
                unsigned short pb = f2bf(p);
                if (r == 0) pk.x = pb; else if (r == 1) pk.y = pb;
                else if (r == 2) pk.z = pb; else pk.w = pb;
            }
            *(ushort4*)&P[wave][c][f * 16 + quad * 4] = pk;
        }
        bc0 = bn0; bc1 = bn1;
        // O += P V
#pragma unroll
        for (int kc = 0; kc < 2; ++kc) {
            short8 pf = *(const short8*)&P[wave][c][kc * 32 + quad * 8];
            Oa0 = __builtin_amdgcn_mfma_f32_16x16x32_bf16(pf, vf0[kc], Oa0, 0, 0, 0);
            Oa1 = __builtin_amdgcn_mfma_f32_16x16x32_bf16(pf, vf1[kc], Oa1, 0, 0, 0);
        }
        // one barrier per tile: protects dbuf + drains staging
        __syncthreads();
    }
    // l-sum: combine the 4 quads (lanes c, c+16, c+32, c+48 share q=c)
    lsum += __shfl_xor(lsum, 16);
    lsum += __shfl_xor(lsum, 32);
    // epilogue: O rows are q=quad*4+r; fetch matching l via shfl from lane rr
#pragma unroll
    for (int r = 0; r < 4; ++r) {
        int rr = quad * 4 + r;
        float invl = 1.0f / __shfl(lsum, rr);
        obuf[(size_t)(m0 + rr) * DD + head * 32 + c]      = (short)f2bf(Oa0[r] * invl);
        obuf[(size_t)(m0 + rr) * DD + head * 32 + 16 + c] = (short)f2bf(Oa1[r] * invl);
    }
}

// ---------------------------------------------------------------------------
// Post kernel, HALF-BLOCK variant: each block owns 8 token rows (half a
// 16-row qtile), grid 512 -> TWO independent barrier domains per CU (the
// R8-proven lever applied to post, which is latency-bound not byte-bound:
// duplicated MFMA rows are free at 5% MfmaUtil; +4MB/layer h re-reads only).
// Rows 8..15 of every tile duplicate rows 0..7 (t_in row&7, h read &7);
// global stores guarded to quad<2 (rr<8). LN sums are per-row -> duplicates
// produce identical values, correctness preserved.
// ---------------------------------------------------------------------------
template <int QKV>
__global__ __launch_bounds__(512) void post_kernel(
    const short* __restrict__ obuf,
    const short* __restrict__ Wta, const short* __restrict__ Wt1,
    const short* __restrict__ Wt2,
    const float* __restrict__ ba, const float* __restrict__ b1,
    const float* __restrict__ b2,
    const float* __restrict__ g1, const float* __restrict__ lb1,
    const float* __restrict__ g2, const float* __restrict__ lb2,
    float* __restrict__ h,
    const short* __restrict__ Wtqn, const short* __restrict__ Wtkn,
    const short* __restrict__ Wtvn,
    const float* __restrict__ bqn, const float* __restrict__ bkn,
    const float* __restrict__ bvn,
    short* __restrict__ qo, short* __restrict__ ko, short* __restrict__ vo)
{
    int tid = threadIdx.x, wave = tid >> 6, lane = tid & 63;
    int quad = lane >> 4, c = lane & 15;
    int bx = blockIdx.x;
    int qtile = bx & 255;         // 16-row qtile index
    int half = bx >> 8;           // which 8-row half
    int m0 = qtile * 16;
    int m0h = m0 + half * 8;      // first valid global token row
    int b = m0 >> 10;
    int q0 = m0 & (NN - 1);
    int q0h = q0 + half * 8;      // first valid in-batch token row
    int nb = wave * 32;

    __shared__ short t_in[16][264];     // 8448 B
    __shared__ short t1s[16][264];      // 8448 B
    __shared__ float shs[8][16][2];     // 1024 B
    const f32x4 zero = {0.f, 0.f, 0.f, 0.f};

    // stage obuf -> t_in (rows 8..15 duplicate rows 0..7)
    {
        int row = tid >> 5, cg = tid & 31;
        *(short8*)&t_in[row][cg * 8] =
            *(const short8*)&obuf[(size_t)(m0h + (row & 7)) * DD + cg * 8];
    }
    __syncthreads();

    // ================= Wa GEMM (A from t_in) ===============================
    f32x4 acc[2] = {zero, zero};
#pragma unroll
    for (int ks = 0; ks < 8; ++ks) {
        short8 af = *(const short8*)&t_in[c][ks * 32 + quad * 8];
#pragma unroll
        for (int f = 0; f < 2; ++f) {
            short8 bf = *(const short8*)&Wta[(size_t)(nb + f * 16 + c) * DD + ks * 32 + quad * 8];
            acc[f] = __builtin_amdgcn_mfma_f32_16x16x32_bf16(af, bf, acc[f], 0, 0, 0);
        }
    }
    // ---- residual + LN1 ----
    float val[2][4];
    float ps[4] = {0.f,0.f,0.f,0.f}, ps2[4] = {0.f,0.f,0.f,0.f};
#pragma unroll
    for (int f = 0; f < 2; ++f) {
        int col = nb + f * 16 + c;
        float bv = ba[col];
#pragma unroll
        for (int r = 0; r < 4; ++r) {
            float v = h[(size_t)(m0h + ((quad * 4 + r) & 7)) * DD + col] + acc[f][r] + bv;
            val[f][r] = v;
            ps[r] += v;
            ps2[r] += v * v;
        }
    }
#pragma unroll
    for (int r = 0; r < 4; ++r)
#pragma unroll
        for (int off = 1; off < 16; off <<= 1) {
            ps[r]  += __shfl_xor(ps[r], off);
            ps2[r] += __shfl_xor(ps2[r], off);
        }
    if (c == 0)
#pragma unroll
        for (int r = 0; r < 4; ++r) {
            shs[wave][quad * 4 + r][0] = ps[r];
            shs[wave][quad * 4 + r][1] = ps2[r];
        }
    __syncthreads();    // also separates Wa t_in reads from LN1 t_in writes
    float res[2][4];
#pragma unroll
    for (int r = 0; r < 4; ++r) {
        int rr = quad * 4 + r;
        float ts = 0.f, t2 = 0.f;
#pragma unroll
        for (int w = 0; w < 8; ++w) { ts += shs[w][rr][0]; t2 += shs[w][rr][1]; }
        float mu = ts * (1.0f / DD);
        float rv = rsqrtf(t2 * (1.0f / DD) - mu * mu + EPSF);
#pragma unroll
        for (int f = 0; f < 2; ++f) {
            int col = nb + f * 16 + c;
            float nv = (val[f][r] - mu) * rv * g1[col] + lb1[col];
            res[f][r] = nv;
            t_in[rr][col] = (short)f2bf(nv);
        }
    }
    __syncthreads();
    // ---- W1 + ReLU -> t1s ----
#pragma unroll
    for (int f = 0; f < 2; ++f) {
        int n0 = nb + f * 16;
        f32x4 a1 = zero;
#pragma unroll
        for (int ks = 0; ks < 8; ++ks) {
            short8 af = *(const short8*)&t_in[c][ks * 32 + quad * 8];
            short8 bf = *(const short8*)&Wt1[(size_t)(n0 + c) * DD + ks * 32 + quad * 8];
            a1 = __builtin_amdgcn_mfma_f32_16x16x32_bf16(af, bf, a1, 0, 0, 0);
        }
        float bv = b1[n0 + c];
#pragma unroll
        for (int r = 0; r < 4; ++r)
            t1s[quad * 4 + r][n0 + c] = (short)f2bf(fmaxf(a1[r] + bv, 0.f));
    }
    __syncthreads();
    // ---- W2 GEMM ----
    f32x4 acc2[2] = {zero, zero};
#pragma unroll
    for (int ks = 0; ks < 8; ++ks) {
        short8 af = *(const short8*)&t1s[c][ks * 32 + quad * 8];
#pragma unroll
        for (int f = 0; f < 2; ++f) {
            short8 bf = *(const short8*)&Wt2[(size_t)(nb + f * 16 + c) * DD + ks * 32 + quad * 8];
            acc2[f] = __builtin_amdgcn_mfma_f32_16x16x32_bf16(af, bf, acc2[f], 0, 0, 0);
        }
    }
    // ---- residual + LN2 ----
    float ps_2[4] = {0.f,0.f,0.f,0.f}, ps2_2[4] = {0.f,0.f,0.f,0.f};
#pragma unroll
    for (int f = 0; f < 2; ++f) {
        int col = nb + f * 16 + c;
        float bv = b2[col];
#pragma unroll
        for (int r = 0; r < 4; ++r) {
            float v = res[f][r] + acc2[f][r] + bv;
            val[f][r] = v;
            ps_2[r] += v;
            ps2_2[r] += v * v;
        }
    }
#pragma unroll
    for (int r = 0; r < 4; ++r)
#pragma unroll
        for (int off = 1; off < 16; off <<= 1) {
            ps_2[r]  += __shfl_xor(ps_2[r], off);
            ps2_2[r] += __shfl_xor(ps2_2[r], off);
        }
    __syncthreads();          // LN1 shs reads complete before overwrite
    if (c == 0)
#pragma unroll
        for (int r = 0; r < 4; ++r) {
            shs[wave][quad * 4 + r][0] = ps_2[r];
            shs[wave][quad * 4 + r][1] = ps2_2[r];
        }
    __syncthreads();
#pragma unroll
    for (int r = 0; r < 4; ++r) {
        int rr = quad * 4 + r;
        float ts = 0.f, t2 = 0.f;
#pragma unroll
        for (int w = 0; w < 8; ++w) { ts += shs[w][rr][0]; t2 += shs[w][rr][1]; }
        float mu = ts * (1.0f / DD);
        float rv = rsqrtf(t2 * (1.0f / DD) - mu * mu + EPSF);
#pragma unroll
        for (int f = 0; f < 2; ++f) {
            int col = nb + f * 16 + c;
            float nv = (val[f][r] - mu) * rv * g2[col] + lb2[col];
            if (quad < 2)                 // rr < 8: valid rows only
                h[(size_t)(m0h + rr) * DD + col] = nv;
            t_in[rr][col] = (short)f2bf(nv);   // stage for next-layer QKV
        }
    }
    if (QKV == 0) return;
    __syncthreads();
    // ================= next-layer QKV from t_in ============================
    {
        int tok0 = q0h + quad * 4;            // valid for quad<2 only
        const short* Wz[3] = {Wtqn, Wtkn, Wtvn};
        const float* bz[3] = {bqn, bkn, bvn};
#pragma unroll
        for (int z = 0; z < 3; ++z) {
#pragma unroll
            for (int f = 0; f < 2; ++f) {
                int n0 = nb + f * 16;
                f32x4 aq = zero;
#pragma unroll
                for (int ks = 0; ks < 8; ++ks) {
                    short8 af = *(const short8*)&t_in[c][ks * 32 + quad * 8];
                    short8 bf = *(const short8*)&Wz[z][(size_t)(n0 + c) * DD + ks * 32 + quad * 8];
                    aq = __builtin_amdgcn_mfma_f32_16x16x32_bf16(af, bf, aq, 0, 0, 0);
                }
                if (quad < 2) {
                    int col = n0 + c;
                    int hd = col >> 5, dk = col & 31;
                    int bh2 = b * 8 + hd;
                    float bv2 = bz[z][col];
                    if (z == 2) {
                        ushort4 pk;
                        pk.x = f2bf(aq[0] + bv2); pk.y = f2bf(aq[1] + bv2);
                        pk.z = f2bf(aq[2] + bv2); pk.w = f2bf(aq[3] + bv2);
                        *(ushort4*)&vo[((size_t)bh2 * DKK + dk) * NN + tok0] = pk;
                    } else {
                        short* out = (z == 0) ? qo : ko;
                        float sc = (z == 0) ? SCLOG2E : 1.0f;
#pragma unroll
                        for (int r = 0; r < 4; ++r)
                            out[((size_t)bh2 * NN + tok0 + r) * DKK + dk] =
                                (short)f2bf((aq[r] + bv2) * sc);
                    }
                }
            }
        }
    }
}

// ---------------------------------------------------------------------------
extern "C" void kernel_launch(void* const* d_in, const int* in_sizes, int n_in,
                              void* d_out, int out_size, void* d_ws, size_t ws_size,
                              hipStream_t stream)
{
    const float* x       = (const float*)d_in[0];
    const int*   deg_in  = (const int*)d_in[1];
    const int*   deg_out = (const int*)d_in[2];
    const int*   sp      = (const int*)d_in[3];
    const float* svd     = (const float*)d_in[4];
    const float* in_emb  = (const float*)d_in[5];
    const float* out_emb = (const float*)d_in[6];
    const float* spemb   = (const float*)d_in[7];
    const float* Wsvd    = (const float*)d_in[8];
    const float* bsvd    = (const float*)d_in[9];
    const float* Wq = (const float*)d_in[10];
    const float* Wk = (const float*)d_in[11];
    const float* Wv = (const float*)d_in[12];
    const float* Wa = (const float*)d_in[13];
    const float* W1 = (const float*)d_in[14];
    const float* W2 = (const float*)d_in[15];
    const float* bq = (const float*)d_in[16];
    const float* bk = (const float*)d_in[17];
    const float* bv = (const float*)d_in[18];
    const float* ba = (const float*)d_in[19];
    const float* b1 = (const float*)d_in[20];
    const float* b2 = (const float*)d_in[21];
    const float* ln1b = (const float*)d_in[22];
    const float* ln2b = (const float*)d_in[23];
    const float* ln1g = (const float*)d_in[24];
    const float* ln2g = (const float*)d_in[25];

    float* h = (float*)d_out;
    char*  ws = (char*)d_ws;
    short* bias = (short*)ws;                         // 16 MB swizzled bf16 bias
    short* qb   = (short*)(ws + ((size_t)16 << 20));  // 2 MB
    short* kb   = (short*)(ws + ((size_t)18 << 20));  // 2 MB
    short* vtb  = (short*)(ws + ((size_t)20 << 20));  // 2 MB
    short* obuf = (short*)(ws + ((size_t)22 << 20));  // 2 MB attention output
    short* hb   = (short*)(ws + ((size_t)26 << 20));  // 2 MB bf16 shadow of h
    short* Wt   = (short*)(ws + ((size_t)28 << 20));  // 3 MB transposed weights

    init_kernel<<<MM, 256, 0, stream>>>(x, deg_in, deg_out, svd, in_emb,
        out_emb, Wsvd, bsvd, Wq, Wk, Wv, Wa, W1, W2, sp, spemb, h, hb, Wt, bias);

    const size_t WSZ = (size_t)DD * DD;
    // layer-0 QKV
    gemm_qkv_kernel<<<dim3(MM / 16, 4, 3), 256, 0, stream>>>(
        hb, Wt + 0 * WSZ, Wt + 4 * WSZ, Wt + 8 * WSZ, bq, bk, bv, qb, kb, vtb);

    for (int l = 0; l < LL; ++l) {
        const size_t bo = (size_t)l * DD;
        const short* Wta = Wt + (3 * 4 + l) * WSZ;
        const short* Wt1 = Wt + (4 * 4 + l) * WSZ;
        const short* Wt2 = Wt + (5 * 4 + l) * WSZ;

        attn_kernel<<<512, 256, 0, stream>>>(qb, kb, vtb, bias, obuf);

        if (l < LL - 1) {
            const size_t bo_n = (size_t)(l + 1) * DD;
            post_kernel<1><<<2 * (MM / 16), 512, 0, stream>>>(
                obuf, Wta, Wt1, Wt2,
                ba + bo, b1 + bo, b2 + bo,
                ln1g + bo, ln1b + bo, ln2g + bo, ln2b + bo, h,
                Wt + (0 * 4 + l + 1) * WSZ, Wt + (1 * 4 + l + 1) * WSZ,
                Wt + (2 * 4 + l + 1) * WSZ,
                bq + bo_n, bk + bo_n, bv + bo_n, qb, kb, vtb);
        } else {
            post_kernel<0><<<2 * (MM / 16), 512, 0, stream>>>(
                obuf, Wta, Wt1, Wt2,
                ba + bo, b1 + bo, b2 + bo,
                ln1g + bo, ln1b + bo, ln2g + bo, ln2b + bo, h,
                nullptr, nullptr, nullptr, nullptr, nullptr, nullptr,
                nullptr, nullptr, nullptr);
        }
    }
}

// Round 12
// 322.323 us; speedup vs baseline: 1.2050x; 1.2050x over previous
//
#include <hip/hip_runtime.h>
#include <hip/hip_bf16.h>
#include <math.h>

#define NN 1024
#define BB 4
#define HH 8
#define DD 256
#define LL 4
#define DKK 32
#define MM 4096
#define EPSF 1e-6f
#define LOG2EF 1.4426950408889634f
#define SCLOG2E 0.2550348625f   /* (1/sqrt(32)) * log2(e) */

typedef __attribute__((ext_vector_type(8))) short short8;
typedef __attribute__((ext_vector_type(4))) float f32x4;
typedef unsigned int u32;

__device__ __forceinline__ unsigned short f2bf(float f) {
    __hip_bfloat16 h = __float2bfloat16(f);
    return *(unsigned short*)&h;
}
__device__ __forceinline__ float bf2f(unsigned short u) {
    unsigned v = ((unsigned)u) << 16;
    return __builtin_bit_cast(float, v);
}

// ---------------------------------------------------------------------------
// init: every block does one prologue row; blocks 0..383 also transpose a
// weight tile; blocks 384..1407 swizzle the bias in the SWAPPED-QK layout
// (verified in R4/R8): value jj=f*4+r at lane (qd,cc) = bias[q=cc][k=kt*64+
// f*16+qd*4+r], pre-scaled by log2(e) for exp2 softmax.
// ---------------------------------------------------------------------------
__global__ __launch_bounds__(256) void init_kernel(
    const float* __restrict__ x, const int* __restrict__ deg_in,
    const int* __restrict__ deg_out, const float* __restrict__ svd,
    const float* __restrict__ in_emb, const float* __restrict__ out_emb,
    const float* __restrict__ Wsvd, const float* __restrict__ bsvd,
    const float* __restrict__ Wq, const float* __restrict__ Wk,
    const float* __restrict__ Wv, const float* __restrict__ Wa,
    const float* __restrict__ W1, const float* __restrict__ W2,
    const int* __restrict__ sp, const float* __restrict__ spemb,
    float* __restrict__ h, short* __restrict__ hb,
    short* __restrict__ Wt, short* __restrict__ bsw)
{
    int blk = blockIdx.x;
    int tid = threadIdx.x;
    {
        int n = blk & (NN - 1);
        int di = deg_in[n], dou = deg_out[n];
        float acc = x[(size_t)blk * DD + tid] + in_emb[(size_t)di * DD + tid]
                  + out_emb[(size_t)dou * DD + tid] + bsvd[tid];
        const float* sv = &svd[n * 32];
#pragma unroll
        for (int j = 0; j < 32; ++j) {
            float v = sv[j];
            v = (j < 16) ? v : -v;
            acc += v * Wsvd[j * DD + tid];
        }
        h[(size_t)blk * DD + tid] = acc;
        hb[(size_t)blk * DD + tid] = (short)f2bf(acc);
    }
    if (blk < 384) {
        __shared__ float t[64][65];
        int z = blk >> 4, tile = blk & 15;
        int name = z >> 2;
        const float* srcs[6] = {Wq, Wk, Wv, Wa, W1, W2};
        const float* W = srcs[name] + (size_t)(z & 3) * DD * DD;
        short* dst = Wt + (size_t)z * DD * DD;
        int r0 = (tile >> 2) * 64, c0 = (tile & 3) * 64;
#pragma unroll
        for (int i = 0; i < 16; ++i) {
            int idx = i * 256 + tid;
            int r = idx >> 6, cc = idx & 63;
            t[r][cc] = W[(size_t)(r0 + r) * DD + c0 + cc];
        }
        __syncthreads();
#pragma unroll
        for (int i = 0; i < 16; ++i) {
            int idx = i * 256 + tid;
            int n = idx >> 6, kk = idx & 63;
            dst[(size_t)(c0 + n) * DD + r0 + kk] = (short)f2bf(t[kk][n]);
        }
    } else if (blk < 1408) {
        int bb = blk - 384;
        int part = bb & 3;                      // f == part
        int tt = (bb >> 2) * 256 + tid;         // (q16, kt, lane)
        int ln = tt & 63, kt = (tt >> 6) & 15, q16 = tt >> 10;
        int qd = ln >> 4, cc = ln & 15;
        int row = q16 * 16 + cc;                // q index (swapped layout)
        unsigned buf[8][2];
#pragma unroll
        for (int r = 0; r < 4; ++r) {
            int colj = kt * 64 + part * 16 + qd * 4 + r;   // k index
            int pp = sp[row * NN + colj];
            float4 e0 = *(const float4*)&spemb[pp * 8];
            float4 e1 = *(const float4*)&spemb[pp * 8 + 4];
            float ev[8] = {e0.x, e0.y, e0.z, e0.w, e1.x, e1.y, e1.z, e1.w};
#pragma unroll
            for (int hh = 0; hh < 8; ++hh) {
                unsigned short u = f2bf(ev[hh] * LOG2EF);
                if (r & 1) buf[hh][r >> 1] |= ((unsigned)u) << 16;
                else       buf[hh][r >> 1] = u;
            }
        }
#pragma unroll
        for (int hh = 0; hh < 8; ++hh) {
            uint2* dst = (uint2*)&bsw[(((size_t)hh * 64 + q16) * 16 + kt) * 1024
                                      + (size_t)ln * 16 + part * 4];
            *dst = make_uint2(buf[hh][0], buf[hh][1]);
        }
    }
}

// ---------------------------------------------------------------------------
// QKV bf16 GEMM (layer 0 only), wave = 16x16 tile. Grid (MM/16, 4, 3).
// q pre-scaled by scale*log2e (exp2 softmax).
// ---------------------------------------------------------------------------
__global__ __launch_bounds__(256) void gemm_qkv_kernel(
    const short* __restrict__ A,
    const short* __restrict__ Wtq, const short* __restrict__ Wtk,
    const short* __restrict__ Wtv,
    const float* __restrict__ bq, const float* __restrict__ bk,
    const float* __restrict__ bv,
    short* __restrict__ qo, short* __restrict__ ko, short* __restrict__ vo)
{
    int z = blockIdx.z;
    const short* Wt = (z == 0) ? Wtq : (z == 1) ? Wtk : Wtv;
    const float* bs = (z == 0) ? bq : (z == 1) ? bk : bv;
    int tid = threadIdx.x, wave = tid >> 6, lane = tid & 63;
    int quad = lane >> 4, c = lane & 15;
    int m0 = blockIdx.x * 16;
    int n0 = blockIdx.y * 64 + wave * 16;
    f32x4 acc = {0.f, 0.f, 0.f, 0.f};
    const short* Ap = &A[(size_t)(m0 + c) * DD];
#pragma unroll
    for (int ks = 0; ks < 8; ++ks) {
        short8 af = *(const short8*)&Ap[ks * 32 + quad * 8];
        short8 bf = *(const short8*)&Wt[(size_t)(n0 + c) * DD + ks * 32 + quad * 8];
        acc = __builtin_amdgcn_mfma_f32_16x16x32_bf16(af, bf, acc, 0, 0, 0);
    }
    int b = m0 >> 10;
    int tok0 = (m0 & (NN - 1)) + quad * 4;
    int col = n0 + c;
    int head = col >> 5, dk = col & 31;
    int bh = b * 8 + head;
    float bv2 = bs[col];
    if (z == 2) {
        ushort4 pk;
        pk.x = f2bf(acc[0] + bv2); pk.y = f2bf(acc[1] + bv2);
        pk.z = f2bf(acc[2] + bv2); pk.w = f2bf(acc[3] + bv2);
        *(ushort4*)&vo[((size_t)bh * DKK + dk) * NN + tok0] = pk;
    } else {
        short* out = (z == 0) ? qo : ko;
        float sc = (z == 0) ? SCLOG2E : 1.0f;
#pragma unroll
        for (int r = 0; r < 4; ++r)
            out[((size_t)bh * NN + tok0 + r) * DKK + dk] =
                (short)f2bf((acc[r] + bv2) * sc);
    }
}

// ---------------------------------------------------------------------------
// Attention kernel: 256 thr = 4 waves (wave = q-tile), grid 512 -> TWO
// independent blocks per CU (decoupled barrier domains). Shared K/V LDS
// staging (4-way reuse). Swapped QK^T (mfma(K,Q)); P transpose = 4x
// ds_write_b64; lane-scalar l-sum. blk%8 == head pins each head's K/V +
// 2MB bias slab to one XCD L2. [R8/R10 configuration — measured best]
// ---------------------------------------------------------------------------
__global__ __launch_bounds__(256) void attn_kernel(
    const short* __restrict__ q, const short* __restrict__ k,
    const short* __restrict__ vt, const short* __restrict__ bsw,
    short* __restrict__ obuf)
{
    int blk = blockIdx.x;
    int head = blk & 7;
    int b = (blk >> 3) & 3;
    int qg = blk >> 5;            // 0..15
    int tid = threadIdx.x, wave = tid >> 6, lane = tid & 63;
    int quad = lane >> 4, c = lane & 15;
    int bh = b * 8 + head;
    int qt = qg * 4 + wave;
    int q0 = qt * 16;
    int m0 = b * NN + q0;

    __shared__ short Ks[2][64][32];   // 8 KB (dbuf K tile, [tok][dk])
    __shared__ short Vs[2][32][64];   // 8 KB (dbuf V tile, [dk][tok])
    __shared__ short P[4][16][72];    // 9.2 KB wave-private P ([q][k], row-major)
    const f32x4 zero = {0.f, 0.f, 0.f, 0.f};

    // stage tile t into buffer buf: each wave stages a K-quarter + V-quarter.
    auto stage = [&](int t, int buf) {
        const short* ksrc = &k[((size_t)bh * NN + t * 64 + wave * 16 + (lane >> 2)) * DKK
                               + (lane & 3) * 8];
        __builtin_amdgcn_global_load_lds(
            (const __attribute__((address_space(1))) u32*)ksrc,
            (__attribute__((address_space(3))) u32*)&Ks[buf][wave * 16][0], 16, 0, 0);
        const short* vsrc = &vt[((size_t)bh * DKK + wave * 8 + (lane >> 3)) * NN
                                + t * 64 + (lane & 7) * 8];
        __builtin_amdgcn_global_load_lds(
            (const __attribute__((address_space(1))) u32*)vsrc,
            (__attribute__((address_space(3))) u32*)&Vs[buf][wave * 8][0], 16, 0, 0);
    };

    stage(0, 0);

    short8 qf = *(const short8*)&q[((size_t)bh * NN + q0 + c) * DKK + quad * 8];
    const short* bbase = &bsw[(((size_t)head * 64 + qt) * 16) * 1024 + (size_t)lane * 16];
    short8 bc0 = *(const short8*)bbase;
    short8 bc1 = *(const short8*)(bbase + 8);

    f32x4 Oa0 = zero, Oa1 = zero;
    float lsum = 0.f;

    __syncthreads();   // tile 0 staged (barrier drains vmcnt)

    for (int kti = 0; kti < 16; ++kti) {
        int cur = kti & 1;
        // issue next tile's staging first (hides under this tile's compute)
        if (kti < 15) stage(kti + 1, cur ^ 1);
        // K fragments (A-operand: K rows) from shared LDS
        short8 kf[4];
#pragma unroll
        for (int f = 0; f < 4; ++f)
            kf[f] = *(const short8*)&Ks[cur][f * 16 + c][quad * 8];
        // V fragments from shared LDS
        short8 vf0[2], vf1[2];
#pragma unroll
        for (int kc = 0; kc < 2; ++kc) {
            vf0[kc] = *(const short8*)&Vs[cur][c][kc * 32 + quad * 8];
            vf1[kc] = *(const short8*)&Vs[cur][16 + c][kc * 32 + quad * 8];
        }
        // S^T = K . Q^T : lane holds S[k=f*16+quad*4+r][q=c]
        f32x4 s[4];
#pragma unroll
        for (int f = 0; f < 4; ++f)
            s[f] = __builtin_amdgcn_mfma_f32_16x16x32_bf16(kf[f], qf, zero, 0, 0, 0);
        // prefetch next bias tile
        short8 bn0 = bc0, bn1 = bc1;
        if (kti < 15) {
            const short* bp = bbase + (size_t)(kti + 1) * 1024;
            bn0 = *(const short8*)bp;
            bn1 = *(const short8*)(bp + 8);
        }
        // exp2(s + bias); pack 4 k-consecutive P values -> one b64 LDS write
#pragma unroll
        for (int f = 0; f < 4; ++f) {
            ushort4 pk;
#pragma unroll
            for (int r = 0; r < 4; ++r) {
                int jj = f * 4 + r;
                unsigned short uu = (unsigned short)((jj < 8) ? bc0[jj] : bc1[jj - 8]);
                float p = __builtin_amdgcn_exp2f(s[f][r] + bf2f(uu));
                lsum += p;
                unsigned short pb = f2bf(p);
                if (r == 0) pk.x = pb; else if (r == 1) pk.y = pb;
                else if (r == 2) pk.z = pb; else pk.w = pb;
            }
            *(ushort4*)&P[wave][c][f * 16 + quad * 4] = pk;
        }
        bc0 = bn0; bc1 = bn1;
        // O += P V
#pragma unroll
        for (int kc = 0; kc < 2; ++kc) {
            short8 pf = *(const short8*)&P[wave][c][kc * 32 + quad * 8];
            Oa0 = __builtin_amdgcn_mfma_f32_16x16x32_bf16(pf, vf0[kc], Oa0, 0, 0, 0);
            Oa1 = __builtin_amdgcn_mfma_f32_16x16x32_bf16(pf, vf1[kc], Oa1, 0, 0, 0);
        }
        // one barrier per tile: protects dbuf + drains staging
        __syncthreads();
    }
    // l-sum: combine the 4 quads (lanes c, c+16, c+32, c+48 share q=c)
    lsum += __shfl_xor(lsum, 16);
    lsum += __shfl_xor(lsum, 32);
    // epilogue: O rows are q=quad*4+r; fetch matching l via shfl from lane rr
#pragma unroll
    for (int r = 0; r < 4; ++r) {
        int rr = quad * 4 + r;
        float invl = 1.0f / __shfl(lsum, rr);
        obuf[(size_t)(m0 + rr) * DD + head * 32 + c]      = (short)f2bf(Oa0[r] * invl);
        obuf[(size_t)(m0 + rr) * DD + head * 32 + 16 + c] = (short)f2bf(Oa1[r] * invl);
    }
}

// ---------------------------------------------------------------------------
// Post kernel (512 thr = 8 waves, 16 token rows, grid 256): stage attention
// output, then Wa+res+LN1 -> W1+ReLU -> W2+res+LN2 [-> next QKV fused].
// ---------------------------------------------------------------------------
template <int QKV>
__global__ __launch_bounds__(512) void post_kernel(
    const short* __restrict__ obuf,
    const short* __restrict__ Wta, const short* __restrict__ Wt1,
    const short* __restrict__ Wt2,
    const float* __restrict__ ba, const float* __restrict__ b1,
    const float* __restrict__ b2,
    const float* __restrict__ g1, const float* __restrict__ lb1,
    const float* __restrict__ g2, const float* __restrict__ lb2,
    float* __restrict__ h,
    const short* __restrict__ Wtqn, const short* __restrict__ Wtkn,
    const short* __restrict__ Wtvn,
    const float* __restrict__ bqn, const float* __restrict__ bkn,
    const float* __restrict__ bvn,
    short* __restrict__ qo, short* __restrict__ ko, short* __restrict__ vo)
{
    int tid = threadIdx.x, wave = tid >> 6, lane = tid & 63;
    int quad = lane >> 4, c = lane & 15;
    int m0 = blockIdx.x * 16;
    int b = m0 >> 10;
    int q0 = m0 & (NN - 1);
    int nb = wave * 32;

    __shared__ short t_in[16][264];     // 8448 B
    __shared__ short t1s[16][264];      // 8448 B
    __shared__ float shs[8][16][2];     // 1024 B
    const f32x4 zero = {0.f, 0.f, 0.f, 0.f};

    // stage obuf -> t_in (coalesced 16B per thread)
    {
        int row = tid >> 5, cg = tid & 31;
        *(short8*)&t_in[row][cg * 8] = *(const short8*)&obuf[(size_t)(m0 + row) * DD + cg * 8];
    }
    __syncthreads();

    // ================= Wa GEMM (A from t_in) ===============================
    f32x4 acc[2] = {zero, zero};
#pragma unroll
    for (int ks = 0; ks < 8; ++ks) {
        short8 af = *(const short8*)&t_in[c][ks * 32 + quad * 8];
#pragma unroll
        for (int f = 0; f < 2; ++f) {
            short8 bf = *(const short8*)&Wta[(size_t)(nb + f * 16 + c) * DD + ks * 32 + quad * 8];
            acc[f] = __builtin_amdgcn_mfma_f32_16x16x32_bf16(af, bf, acc[f], 0, 0, 0);
        }
    }
    // ---- residual + LN1 ----
    float val[2][4];
    float ps[4] = {0.f,0.f,0.f,0.f}, ps2[4] = {0.f,0.f,0.f,0.f};
#pragma unroll
    for (int f = 0; f < 2; ++f) {
        int col = nb + f * 16 + c;
        float bv = ba[col];
#pragma unroll
        for (int r = 0; r < 4; ++r) {
            float v = h[(size_t)(m0 + quad * 4 + r) * DD + col] + acc[f][r] + bv;
            val[f][r] = v;
            ps[r] += v;
            ps2[r] += v * v;
        }
    }
#pragma unroll
    for (int r = 0; r < 4; ++r)
#pragma unroll
        for (int off = 1; off < 16; off <<= 1) {
            ps[r]  += __shfl_xor(ps[r], off);
            ps2[r] += __shfl_xor(ps2[r], off);
        }
    if (c == 0)
#pragma unroll
        for (int r = 0; r < 4; ++r) {
            shs[wave][quad * 4 + r][0] = ps[r];
            shs[wave][quad * 4 + r][1] = ps2[r];
        }
    __syncthreads();    // also separates Wa t_in reads from LN1 t_in writes
    float res[2][4];
#pragma unroll
    for (int r = 0; r < 4; ++r) {
        int rr = quad * 4 + r;
        float ts = 0.f, t2 = 0.f;
#pragma unroll
        for (int w = 0; w < 8; ++w) { ts += shs[w][rr][0]; t2 += shs[w][rr][1]; }
        float mu = ts * (1.0f / DD);
        float rv = rsqrtf(t2 * (1.0f / DD) - mu * mu + EPSF);
#pragma unroll
        for (int f = 0; f < 2; ++f) {
            int col = nb + f * 16 + c;
            float nv = (val[f][r] - mu) * rv * g1[col] + lb1[col];
            res[f][r] = nv;
            t_in[rr][col] = (short)f2bf(nv);
        }
    }
    __syncthreads();
    // ---- W1 + ReLU -> t1s ----
#pragma unroll
    for (int f = 0; f < 2; ++f) {
        int n0 = nb + f * 16;
        f32x4 a1 = zero;
#pragma unroll
        for (int ks = 0; ks < 8; ++ks) {
            short8 af = *(const short8*)&t_in[c][ks * 32 + quad * 8];
            short8 bf = *(const short8*)&Wt1[(size_t)(n0 + c) * DD + ks * 32 + quad * 8];
            a1 = __builtin_amdgcn_mfma_f32_16x16x32_bf16(af, bf, a1, 0, 0, 0);
        }
        float bv = b1[n0 + c];
#pragma unroll
        for (int r = 0; r < 4; ++r)
            t1s[quad * 4 + r][n0 + c] = (short)f2bf(fmaxf(a1[r] + bv, 0.f));
    }
    __syncthreads();
    // ---- W2 GEMM ----
    f32x4 acc2[2] = {zero, zero};
#pragma unroll
    for (int ks = 0; ks < 8; ++ks) {
        short8 af = *(const short8*)&t1s[c][ks * 32 + quad * 8];
#pragma unroll
        for (int f = 0; f < 2; ++f) {
            short8 bf = *(const short8*)&Wt2[(size_t)(nb + f * 16 + c) * DD + ks * 32 + quad * 8];
            acc2[f] = __builtin_amdgcn_mfma_f32_16x16x32_bf16(af, bf, acc2[f], 0, 0, 0);
        }
    }
    // ---- residual + LN2 ----
    float ps_2[4] = {0.f,0.f,0.f,0.f}, ps2_2[4] = {0.f,0.f,0.f,0.f};
#pragma unroll
    for (int f = 0; f < 2; ++f) {
        int col = nb + f * 16 + c;
        float bv = b2[col];
#pragma unroll
        for (int r = 0; r < 4; ++r) {
            float v = res[f][r] + acc2[f][r] + bv;
            val[f][r] = v;
            ps_2[r] += v;
            ps2_2[r] += v * v;
        }
    }
#pragma unroll
    for (int r = 0; r < 4; ++r)
#pragma unroll
        for (int off = 1; off < 16; off <<= 1) {
            ps_2[r]  += __shfl_xor(ps_2[r], off);
            ps2_2[r] += __shfl_xor(ps2_2[r], off);
        }
    __syncthreads();          // LN1 shs reads complete before overwrite
    if (c == 0)
#pragma unroll
        for (int r = 0; r < 4; ++r) {
            shs[wave][quad * 4 + r][0] = ps_2[r];
            shs[wave][quad * 4 + r][1] = ps2_2[r];
        }
    __syncthreads();
#pragma unroll
    for (int r = 0; r < 4; ++r) {
        int rr = quad * 4 + r;
        float ts = 0.f, t2 = 0.f;
#pragma unroll
        for (int w = 0; w < 8; ++w) { ts += shs[w][rr][0]; t2 += shs[w][rr][1]; }
        float mu = ts * (1.0f / DD);
        float rv = rsqrtf(t2 * (1.0f / DD) - mu * mu + EPSF);
#pragma unroll
        for (int f = 0; f < 2; ++f) {
            int col = nb + f * 16 + c;
            float nv = (val[f][r] - mu) * rv * g2[col] + lb2[col];
            h[(size_t)(m0 + rr) * DD + col] = nv;
            t_in[rr][col] = (short)f2bf(nv);   // stage for next-layer QKV
        }
    }
    if (QKV == 0) return;
    __syncthreads();
    // ================= next-layer QKV from t_in ============================
    {
        int tok0 = q0 + quad * 4;
        const short* Wz[3] = {Wtqn, Wtkn, Wtvn};
        const float* bz[3] = {bqn, bkn, bvn};
#pragma unroll
        for (int z = 0; z < 3; ++z) {
#pragma unroll
            for (int f = 0; f < 2; ++f) {
                int n0 = nb + f * 16;
                f32x4 aq = zero;
#pragma unroll
                for (int ks = 0; ks < 8; ++ks) {
                    short8 af = *(const short8*)&t_in[c][ks * 32 + quad * 8];
                    short8 bf = *(const short8*)&Wz[z][(size_t)(n0 + c) * DD + ks * 32 + quad * 8];
                    aq = __builtin_amdgcn_mfma_f32_16x16x32_bf16(af, bf, aq, 0, 0, 0);
                }
                int col = n0 + c;
                int hd = col >> 5, dk = col & 31;
                int bh2 = b * 8 + hd;
                float bv2 = bz[z][col];
                if (z == 2) {
                    ushort4 pk;
                    pk.x = f2bf(aq[0] + bv2); pk.y = f2bf(aq[1] + bv2);
                    pk.z = f2bf(aq[2] + bv2); pk.w = f2bf(aq[3] + bv2);
                    *(ushort4*)&vo[((size_t)bh2 * DKK + dk) * NN + tok0] = pk;
                } else {
                    short* out = (z == 0) ? qo : ko;
                    float sc = (z == 0) ? SCLOG2E : 1.0f;
#pragma unroll
                    for (int r = 0; r < 4; ++r)
                        out[((size_t)bh2 * NN + tok0 + r) * DKK + dk] =
                            (short)f2bf((aq[r] + bv2) * sc);
                }
            }
        }
    }
}

// ---------------------------------------------------------------------------
extern "C" void kernel_launch(void* const* d_in, const int* in_sizes, int n_in,
                              void* d_out, int out_size, void* d_ws, size_t ws_size,
                              hipStream_t stream)
{
    const float* x       = (const float*)d_in[0];
    const int*   deg_in  = (const int*)d_in[1];
    const int*   deg_out = (const int*)d_in[2];
    const int*   sp      = (const int*)d_in[3];
    const float* svd     = (const float*)d_in[4];
    const float* in_emb  = (const float*)d_in[5];
    const float* out_emb = (const float*)d_in[6];
    const float* spemb   = (const float*)d_in[7];
    const float* Wsvd    = (const float*)d_in[8];
    const float* bsvd    = (const float*)d_in[9];
    const float* Wq = (const float*)d_in[10];
    const float* Wk = (const float*)d_in[11];
    const float* Wv = (const float*)d_in[12];
    const float* Wa = (const float*)d_in[13];
    const float* W1 = (const float*)d_in[14];
    const float* W2 = (const float*)d_in[15];
    const float* bq = (const float*)d_in[16];
    const float* bk = (const float*)d_in[17];
    const float* bv = (const float*)d_in[18];
    const float* ba = (const float*)d_in[19];
    const float* b1 = (const float*)d_in[20];
    const float* b2 = (const float*)d_in[21];
    const float* ln1b = (const float*)d_in[22];
    const float* ln2b = (const float*)d_in[23];
    const float* ln1g = (const float*)d_in[24];
    const float* ln2g = (const float*)d_in[25];

    float* h = (float*)d_out;
    char*  ws = (char*)d_ws;
    short* bias = (short*)ws;                         // 16 MB swizzled bf16 bias
    short* qb   = (short*)(ws + ((size_t)16 << 20));  // 2 MB
    short* kb   = (short*)(ws + ((size_t)18 << 20));  // 2 MB
    short* vtb  = (short*)(ws + ((size_t)20 << 20));  // 2 MB
    short* obuf = (short*)(ws + ((size_t)22 << 20));  // 2 MB attention output
    short* hb   = (short*)(ws + ((size_t)26 << 20));  // 2 MB bf16 shadow of h
    short* Wt   = (short*)(ws + ((size_t)28 << 20));  // 3 MB transposed weights

    init_kernel<<<MM, 256, 0, stream>>>(x, deg_in, deg_out, svd, in_emb,
        out_emb, Wsvd, bsvd, Wq, Wk, Wv, Wa, W1, W2, sp, spemb, h, hb, Wt, bias);

    const size_t WSZ = (size_t)DD * DD;
    // layer-0 QKV
    gemm_qkv_kernel<<<dim3(MM / 16, 4, 3), 256, 0, stream>>>(
        hb, Wt + 0 * WSZ, Wt + 4 * WSZ, Wt + 8 * WSZ, bq, bk, bv, qb, kb, vtb);

    for (int l = 0; l < LL; ++l) {
        const size_t bo = (size_t)l * DD;
        const short* Wta = Wt + (3 * 4 + l) * WSZ;
        const short* Wt1 = Wt + (4 * 4 + l) * WSZ;
        const short* Wt2 = Wt + (5 * 4 + l) * WSZ;

        attn_kernel<<<512, 256, 0, stream>>>(qb, kb, vtb, bias, obuf);

        if (l < LL - 1) {
            const size_t bo_n = (size_t)(l + 1) * DD;
            post_kernel<1><<<MM / 16, 512, 0, stream>>>(
                obuf, Wta, Wt1, Wt2,
                ba + bo, b1 + bo, b2 + bo,
                ln1g + bo, ln1b + bo, ln2g + bo, ln2b + bo, h,
                Wt + (0 * 4 + l + 1) * WSZ, Wt + (1 * 4 + l + 1) * WSZ,
                Wt + (2 * 4 + l + 1) * WSZ,
                bq + bo_n, bk + bo_n, bv + bo_n, qb, kb, vtb);
        } else {
            post_kernel<0><<<MM / 16, 512, 0, stream>>>(
                obuf, Wta, Wt1, Wt2,
                ba + bo, b1 + bo, b2 + bo,
                ln1g + bo, ln1b + bo, ln2g + bo, ln2b + bo, h,
                nullptr, nullptr, nullptr, nullptr, nullptr, nullptr,
                nullptr, nullptr, nullptr);
        }
    }
}